// Round 15
// baseline (84.346 us; speedup 1.0000x reference)
//
#include <hip/hip_runtime.h>

namespace {
constexpr int kC = 1025;
constexpr int kT = 3000;
constexpr int kThreads = 256;              // 4 waves; 1 row per block
constexpr int kWSeg = 768;                 // elements per wave (4*768 >= 3000)
constexpr int kSub = 256;                  // elements per (wave, s) sub-segment
constexpr int kNS = 3;                     // sub-segments per lane
constexpr int kGridB = 8200;               // one block per row
constexpr float kPi = 3.14159265358979323846f;   // 0x40490FDB == np.float32(np.pi)
constexpr float kTwoPi = 6.28318530717958647692f;
constexpr float kPiO2 = 1.57079632679489661923f;
constexpr float kInv2Pi = 0.15915494309189533577f;
}  // namespace

typedef float v4f __attribute__((ext_vector_type(4)));
typedef float v2f __attribute__((ext_vector_type(2)));

// Raw barrier: orders LDS (lgkmcnt) only; global loads/stores stay in flight.
__device__ __forceinline__ void sync_lds() {
  asm volatile("s_waitcnt lgkmcnt(0)" ::: "memory");
  __builtin_amdgcn_s_barrier();
  asm volatile("" ::: "memory");
}

__device__ __forceinline__ float rdlane_f(float v, int l) {
  return __builtin_bit_cast(
      float, __builtin_amdgcn_readlane(__builtin_bit_cast(int, v), l));
}

// DPP lane-permute on the VALU pipe (no LDS traffic).
template <int kCtrl>
__device__ __forceinline__ float dpp_f(float v) {
  return __builtin_bit_cast(
      float, __builtin_amdgcn_update_dpp(__builtin_bit_cast(int, v),
                                         __builtin_bit_cast(int, v), kCtrl,
                                         0xF, 0xF, false));
}

// Full-wave min/max; result valid in lane 63. (Verified numerically in R8.)
__device__ __forceinline__ void wave_minmax63(float& mn, float& mx) {
  mn = fminf(mn, dpp_f<0x121>(mn)); mx = fmaxf(mx, dpp_f<0x121>(mx));
  mn = fminf(mn, dpp_f<0x122>(mn)); mx = fmaxf(mx, dpp_f<0x122>(mx));
  mn = fminf(mn, dpp_f<0x124>(mn)); mx = fmaxf(mx, dpp_f<0x124>(mx));
  mn = fminf(mn, dpp_f<0x128>(mn)); mx = fmaxf(mx, dpp_f<0x128>(mx));
  mn = fminf(mn, dpp_f<0x142>(mn)); mx = fmaxf(mx, dpp_f<0x142>(mx));
  mn = fminf(mn, dpp_f<0x143>(mn)); mx = fmaxf(mx, dpp_f<0x143>(mx));
}

// atan core on t in [0,1], 2 lanes packed -> v_pk_fma_f32 candidates.
__device__ __forceinline__ v2f atan_core2(v2f t) {
  const v2f s = t * t;
  v2f p = v2f{0.00282363896258175373f, 0.00282363896258175373f};
  p = p * s + v2f{-0.0159569028764963150f, -0.0159569028764963150f};
  p = p * s + v2f{0.0425049886107444763f, 0.0425049886107444763f};
  p = p * s + v2f{-0.0748900920152664185f, -0.0748900920152664185f};
  p = p * s + v2f{0.106347933411598206f, 0.106347933411598206f};
  p = p * s + v2f{-0.142027363181114197f, -0.142027363181114197f};
  p = p * s + v2f{0.199926957488059998f, 0.199926957488059998f};
  p = p * s + v2f{-0.333331018686294556f, -0.333331018686294556f};
  return (p * s) * t + t;
}

__device__ __forceinline__ void fast_atan2_4(const v4f y4, const v4f x4,
                                             float out[4]) {
  float t[4], ax[4], ay[4];
  const float xs[4] = {x4.x, x4.y, x4.z, x4.w};
  const float ys[4] = {y4.x, y4.y, y4.z, y4.w};
#pragma unroll
  for (int k = 0; k < 4; ++k) {
    ax[k] = __builtin_fabsf(xs[k]);
    ay[k] = __builtin_fabsf(ys[k]);
    const float mx = fmaxf(ax[k], ay[k]);
    const float mn = fminf(ax[k], ay[k]);
    float tt = mn * __builtin_amdgcn_rcpf(mx);
    if (mx == 0.0f) tt = 0.0f;             // atan2(0,0) -> 0 (avoid 0*inf NaN)
    t[k] = tt;
  }
  const v2f a01 = atan_core2(v2f{t[0], t[1]});
  const v2f a23 = atan_core2(v2f{t[2], t[3]});
  const float av[4] = {a01.x, a01.y, a23.x, a23.y};
#pragma unroll
  for (int k = 0; k < 4; ++k) {
    float a = av[k];
    a = (ay[k] > ax[k]) ? (kPiO2 - a) : a;
    a = (xs[k] < 0.0f) ? (kPi - a) : a;
    out[k] = copysignf(a, ys[k]);
  }
}

// A/B vs R14: plain cached stores instead of nontemporal. Evidence: every
// high-BW writer on this chip (fill kernel 7 TB/s, m13 copy 6.3 TB/s) uses
// cached stores; nt (no-allocate) removes L2's elastic write buffering and
// couples store drain into the wave critical path (R14: dur ~= mem + VALU,
// no overlap).
__global__ __launch_bounds__(kThreads) void coherent_polar_kernel(
    const float* __restrict__ xr, const float* __restrict__ xi,
    float* __restrict__ out) {
  // Tiny cross-wave exchange: [{head,tail,tot,min,max}][wave].
  __shared__ __align__(16) float s_comb[5][4];

  const int row = blockIdx.x;              // [0, 8200)
  const int tid = threadIdx.x;
  const int lane = tid & 63;
  const int wave = tid >> 6;

  const int b = row / kC;
  const int c = row - b * kC;
  const float* re = xr + (size_t)row * kT;
  const float* im = xi + (size_t)row * kT;
  float* mag_out = out + ((size_t)b * (2 * kC) + c) * kT;
  float* ph_out  = out + ((size_t)b * (2 * kC) + kC + c) * kT;

  // Wave-local layout: wave w owns [768w, 768w+768); lane l, sub-seg s at
  // 768w + 256s + 4l (each (w,s) instruction covers 1KB contiguous).
  int offs[kNS];
  bool act[kNS];
#pragma unroll
  for (int s = 0; s < kNS; ++s) {
    offs[s] = wave * kWSeg + s * kSub + lane * 4;
    act[s] = offs[s] < kT;                 // only (wave3, s2, lane>=46) is off
  }
  const int tail_lane = (wave == 3) ? 45 : 63;   // lane holding wave's last elem

  // ---- Loads (wave-contiguous 1KB per instruction).
  v4f r4[kNS], i4[kNS];
#pragma unroll
  for (int s = 0; s < kNS; ++s) {
    if (act[s]) {
      r4[s] = *reinterpret_cast<const v4f*>(re + offs[s]);
      i4[s] = *reinterpret_cast<const v4f*>(im + offs[s]);
    }
  }

  // ---- Magnitude out (cached, coalesced) + raw phases to registers.
  float ph[kNS][4];
#pragma unroll
  for (int s = 0; s < kNS; ++s) {
    if (act[s]) {
      v4f m4;
      m4.x = __builtin_amdgcn_sqrtf(fmaf(r4[s].x, r4[s].x, i4[s].x * i4[s].x));
      m4.y = __builtin_amdgcn_sqrtf(fmaf(r4[s].y, r4[s].y, i4[s].y * i4[s].y));
      m4.z = __builtin_amdgcn_sqrtf(fmaf(r4[s].z, r4[s].z, i4[s].z * i4[s].z));
      m4.w = __builtin_amdgcn_sqrtf(fmaf(r4[s].w, r4[s].w, i4[s].w * i4[s].w));
      *reinterpret_cast<v4f*>(mag_out + offs[s]) = m4;
      fast_atan2_4(i4[s], r4[s], ph[s]);
    }
  }

  // ---- Raw boundary values (before correction).
  const float rawhead = ph[0][0];          // lane 0: wave head
  float rawtail[kNS];
#pragma unroll
  for (int s = 0; s < kNS; ++s) rawtail[s] = ph[s][3];

  // Predecessor phase for chunk (s, lane) — all wave-internal:
  float prev[kNS];
#pragma unroll
  for (int s = 0; s < kNS; ++s) {
    float pv = __shfl_up(rawtail[s], 1);
    if (lane == 0)
      pv = (s == 0) ? rawhead : rdlane_f(rawtail[s - 1], 63);
    prev[s] = pv;                          // wave-start boundary: step 0 here,
  }                                        // fixed up in the combine below.

  // ---- Local unwrap; exact per-chunk step counts.
  int n[kNS];
#pragma unroll
  for (int s = 0; s < kNS; ++s) {
    float run = 0.0f;
    if (act[s]) {
      float p = prev[s];
#pragma unroll
      for (int k = 0; k < 4; ++k) {
        const float cur = ph[s][k];
        const float d = cur - p;
        p = cur;
        float step = 0.0f;
        if (d < -kPi) step = kTwoPi;
        else if (d > kPi) step = -kTwoPi;
        run += step;
        ph[s][k] = cur + run;
      }
    }
    n[s] = __float2int_rn(run * kInv2Pi);  // exact: |n| <= 4
  }

  // ---- ONE packed-int wave scan (3 x 10-bit biased fields, no carries).
  const unsigned packed = (unsigned)(n[0] + 8) |
                          ((unsigned)(n[1] + 8) << 10) |
                          ((unsigned)(n[2] + 8) << 20);
  unsigned incp = packed;
#pragma unroll
  for (int d = 1; d < 64; d <<= 1) {
    const unsigned up = (unsigned)__shfl_up((int)incp, d);
    if (lane >= d) incp += up;
  }
  const unsigned excp = incp - packed;     // exclusive, field-wise
  const unsigned i63 = (unsigned)__builtin_amdgcn_readlane((int)incp, 63);
  const int tot0 = (int)(i63 & 1023u) - 512;
  const int tot1 = (int)((i63 >> 10) & 1023u) - 512;
  const int tot2 = (int)((i63 >> 20) & 1023u) - 512;
  // within-wave correction count for chunk (s, lane):
  int cnt[kNS];
  cnt[0] = (int)(excp & 1023u) - 8 * lane;
  cnt[1] = (int)((excp >> 10) & 1023u) - 8 * lane + tot0;
  cnt[2] = (int)((excp >> 20) & 1023u) - 8 * lane + tot0 + tot1;

  // ---- Per-lane min/max over corrected values; DPP wave reduce.
  float mn = __builtin_inff();
  float mx = -__builtin_inff();
  float woff[kNS];
#pragma unroll
  for (int s = 0; s < kNS; ++s) {
    woff[s] = (float)cnt[s] * kTwoPi;
    if (act[s]) {
#pragma unroll
      for (int k = 0; k < 4; ++k) {
        const float u = ph[s][k] + woff[s];
        mn = fminf(mn, u);
        mx = fmaxf(mx, u);
      }
    }
  }
  wave_minmax63(mn, mx);

  // ---- Publish 5 floats per wave; one barrier.
  const float tailv = rdlane_f(rawtail[2], tail_lane);   // wave's last raw phase
  const float headv = rdlane_f(rawhead, 0);
  if (lane == 63) {
    s_comb[0][wave] = headv;
    s_comb[1][wave] = tailv;
    s_comb[2][wave] = (float)(tot0 + tot1 + tot2);
    s_comb[3][wave] = mn;
    s_comb[4][wave] = mx;
  }
  sync_lds();   // the only barrier (lgkm only)

  // ---- Combine (all threads redundantly; 5 x ds_read_b128).
  const v4f hd = *reinterpret_cast<const v4f*>(&s_comb[0][0]);
  const v4f tl = *reinterpret_cast<const v4f*>(&s_comb[1][0]);
  const v4f tw = *reinterpret_cast<const v4f*>(&s_comb[2][0]);
  const v4f wm = *reinterpret_cast<const v4f*>(&s_comb[3][0]);
  const v4f wx = *reinterpret_cast<const v4f*>(&s_comb[4][0]);

  // wave-boundary steps (same predicate as reference) + cumulative counts
  float C[4];
  C[0] = 0.0f;
  {
    float cum = 0.0f;
    const float hds[4] = {hd.x, hd.y, hd.z, hd.w};
    const float tls[4] = {tl.x, tl.y, tl.z, tl.w};
    const float tws[4] = {tw.x, tw.y, tw.z, tw.w};
#pragma unroll
    for (int w = 1; w < 4; ++w) {
      const float d = hds[w] - tls[w - 1];
      float nb = 0.0f;
      if (d < -kPi) nb = 1.0f;
      else if (d > kPi) nb = -1.0f;
      cum += tws[w - 1] + nb;
      C[w] = cum;
    }
  }
  const float wms[4] = {wm.x, wm.y, wm.z, wm.w};
  const float wxs[4] = {wx.x, wx.y, wx.z, wx.w};
  float gmn = __builtin_inff();
  float gmx = -__builtin_inff();
#pragma unroll
  for (int w = 0; w < 4; ++w) {
    gmn = fminf(gmn, wms[w] + C[w] * kTwoPi);
    gmx = fmaxf(gmx, wxs[w] + C[w] * kTwoPi);
  }
  const float inv = 1.0f / (gmx - gmn + 1e-8f);
  const float myC = C[wave] * kTwoPi;

  // ---- Normalized phase out (cached, coalesced).
#pragma unroll
  for (int s = 0; s < kNS; ++s) {
    if (act[s]) {
      const float base = myC + woff[s] - gmn;
      v4f o;
      o.x = (ph[s][0] + base) * inv;
      o.y = (ph[s][1] + base) * inv;
      o.z = (ph[s][2] + base) * inv;
      o.w = (ph[s][3] + base) * inv;
      *reinterpret_cast<v4f*>(ph_out + offs[s]) = o;
    }
  }
}

extern "C" void kernel_launch(void* const* d_in, const int* in_sizes, int n_in,
                              void* d_out, int out_size, void* d_ws, size_t ws_size,
                              hipStream_t stream) {
  const float* xr = (const float*)d_in[0];
  const float* xi = (const float*)d_in[1];
  float* out = (float*)d_out;
  coherent_polar_kernel<<<dim3(kGridB), dim3(kThreads), 0, stream>>>(xr, xi, out);
}

// Round 16
// 65.339 us; speedup vs baseline: 1.2909x; 1.2909x over previous
//
#include <hip/hip_runtime.h>

namespace {
constexpr int kC = 1025;
constexpr int kT = 3000;
constexpr int kThreads = 256;              // 4 waves; 1 row per block
constexpr int kWSeg = 768;                 // elements per wave (4*768 >= 3000)
constexpr int kSub = 256;                  // elements per (wave, s) sub-segment
constexpr int kNS = 3;                     // sub-segments per lane
constexpr int kGridB = 8200;               // one block per row
constexpr float kPi = 3.14159265358979323846f;   // 0x40490FDB == np.float32(np.pi)
constexpr float kTwoPi = 6.28318530717958647692f;
constexpr float kPiO2 = 1.57079632679489661923f;
constexpr float kInv2Pi = 0.15915494309189533577f;
}  // namespace

typedef float v4f __attribute__((ext_vector_type(4)));
typedef float v2f __attribute__((ext_vector_type(2)));

// Raw barrier: orders LDS (lgkmcnt) only; global loads/stores stay in flight.
__device__ __forceinline__ void sync_lds() {
  asm volatile("s_waitcnt lgkmcnt(0)" ::: "memory");
  __builtin_amdgcn_s_barrier();
  asm volatile("" ::: "memory");
}

__device__ __forceinline__ float rdlane_f(float v, int l) {
  return __builtin_bit_cast(
      float, __builtin_amdgcn_readlane(__builtin_bit_cast(int, v), l));
}

// DPP lane-permute on the VALU pipe (no LDS traffic).
template <int kCtrl>
__device__ __forceinline__ float dpp_f(float v) {
  return __builtin_bit_cast(
      float, __builtin_amdgcn_update_dpp(__builtin_bit_cast(int, v),
                                         __builtin_bit_cast(int, v), kCtrl,
                                         0xF, 0xF, false));
}

// Full-wave min/max; result valid in lane 63. (Verified numerically in R8.)
__device__ __forceinline__ void wave_minmax63(float& mn, float& mx) {
  mn = fminf(mn, dpp_f<0x121>(mn)); mx = fmaxf(mx, dpp_f<0x121>(mx));
  mn = fminf(mn, dpp_f<0x122>(mn)); mx = fmaxf(mx, dpp_f<0x122>(mx));
  mn = fminf(mn, dpp_f<0x124>(mn)); mx = fmaxf(mx, dpp_f<0x124>(mx));
  mn = fminf(mn, dpp_f<0x128>(mn)); mx = fmaxf(mx, dpp_f<0x128>(mx));
  mn = fminf(mn, dpp_f<0x142>(mn)); mx = fmaxf(mx, dpp_f<0x142>(mx));
  mn = fminf(mn, dpp_f<0x143>(mn)); mx = fmaxf(mx, dpp_f<0x143>(mx));
}

// atan core on t in [0,1], 2 lanes packed -> v_pk_fma_f32 candidates.
__device__ __forceinline__ v2f atan_core2(v2f t) {
  const v2f s = t * t;
  v2f p = v2f{0.00282363896258175373f, 0.00282363896258175373f};
  p = p * s + v2f{-0.0159569028764963150f, -0.0159569028764963150f};
  p = p * s + v2f{0.0425049886107444763f, 0.0425049886107444763f};
  p = p * s + v2f{-0.0748900920152664185f, -0.0748900920152664185f};
  p = p * s + v2f{0.106347933411598206f, 0.106347933411598206f};
  p = p * s + v2f{-0.142027363181114197f, -0.142027363181114197f};
  p = p * s + v2f{0.199926957488059998f, 0.199926957488059998f};
  p = p * s + v2f{-0.333331018686294556f, -0.333331018686294556f};
  return (p * s) * t + t;
}

__device__ __forceinline__ void fast_atan2_4(const v4f y4, const v4f x4,
                                             float out[4]) {
  float t[4], ax[4], ay[4];
  const float xs[4] = {x4.x, x4.y, x4.z, x4.w};
  const float ys[4] = {y4.x, y4.y, y4.z, y4.w};
#pragma unroll
  for (int k = 0; k < 4; ++k) {
    ax[k] = __builtin_fabsf(xs[k]);
    ay[k] = __builtin_fabsf(ys[k]);
    const float mx = fmaxf(ax[k], ay[k]);
    const float mn = fminf(ax[k], ay[k]);
    float tt = mn * __builtin_amdgcn_rcpf(mx);
    if (mx == 0.0f) tt = 0.0f;             // atan2(0,0) -> 0 (avoid 0*inf NaN)
    t[k] = tt;
  }
  const v2f a01 = atan_core2(v2f{t[0], t[1]});
  const v2f a23 = atan_core2(v2f{t[2], t[3]});
  const float av[4] = {a01.x, a01.y, a23.x, a23.y};
#pragma unroll
  for (int k = 0; k < 4; ++k) {
    float a = av[k];
    a = (ay[k] > ax[k]) ? (kPiO2 - a) : a;
    a = (xs[k] < 0.0f) ? (kPi - a) : a;
    out[k] = copysignf(a, ys[k]);
  }
}

// R14 configuration (best, 65.5us): 1 row/block, VGPR 28, occupancy 77%,
// NONTEMPORAL stores (A/B vs cached: 65.5 vs 84.3 — nt keeps the zero-reuse
// write streams from churning L2/L3, which serves ~half the input reads).
// min-waves launch_bounds hints spill pathologically (R11/R12) — omit.
__global__ __launch_bounds__(kThreads) void coherent_polar_kernel(
    const float* __restrict__ xr, const float* __restrict__ xi,
    float* __restrict__ out) {
  // Tiny cross-wave exchange: [{head,tail,tot,min,max}][wave].
  __shared__ __align__(16) float s_comb[5][4];

  const int row = blockIdx.x;              // [0, 8200)
  const int tid = threadIdx.x;
  const int lane = tid & 63;
  const int wave = tid >> 6;

  const int b = row / kC;
  const int c = row - b * kC;
  const float* re = xr + (size_t)row * kT;
  const float* im = xi + (size_t)row * kT;
  float* mag_out = out + ((size_t)b * (2 * kC) + c) * kT;
  float* ph_out  = out + ((size_t)b * (2 * kC) + kC + c) * kT;

  // Wave-local layout: wave w owns [768w, 768w+768); lane l, sub-seg s at
  // 768w + 256s + 4l (each (w,s) instruction covers 1KB contiguous).
  int offs[kNS];
  bool act[kNS];
#pragma unroll
  for (int s = 0; s < kNS; ++s) {
    offs[s] = wave * kWSeg + s * kSub + lane * 4;
    act[s] = offs[s] < kT;                 // only (wave3, s2, lane>=46) is off
  }
  const int tail_lane = (wave == 3) ? 45 : 63;   // lane holding wave's last elem

  // ---- Loads (wave-contiguous 1KB per instruction).
  v4f r4[kNS], i4[kNS];
#pragma unroll
  for (int s = 0; s < kNS; ++s) {
    if (act[s]) {
      r4[s] = *reinterpret_cast<const v4f*>(re + offs[s]);
      i4[s] = *reinterpret_cast<const v4f*>(im + offs[s]);
    }
  }

  // ---- Magnitude out (nt, coalesced) + raw phases to registers.
  float ph[kNS][4];
#pragma unroll
  for (int s = 0; s < kNS; ++s) {
    if (act[s]) {
      v4f m4;
      m4.x = __builtin_amdgcn_sqrtf(fmaf(r4[s].x, r4[s].x, i4[s].x * i4[s].x));
      m4.y = __builtin_amdgcn_sqrtf(fmaf(r4[s].y, r4[s].y, i4[s].y * i4[s].y));
      m4.z = __builtin_amdgcn_sqrtf(fmaf(r4[s].z, r4[s].z, i4[s].z * i4[s].z));
      m4.w = __builtin_amdgcn_sqrtf(fmaf(r4[s].w, r4[s].w, i4[s].w * i4[s].w));
      __builtin_nontemporal_store(m4, reinterpret_cast<v4f*>(mag_out + offs[s]));
      fast_atan2_4(i4[s], r4[s], ph[s]);
    }
  }

  // ---- Raw boundary values (before correction).
  const float rawhead = ph[0][0];          // lane 0: wave head
  float rawtail[kNS];
#pragma unroll
  for (int s = 0; s < kNS; ++s) rawtail[s] = ph[s][3];

  // Predecessor phase for chunk (s, lane) — all wave-internal:
  float prev[kNS];
#pragma unroll
  for (int s = 0; s < kNS; ++s) {
    float pv = __shfl_up(rawtail[s], 1);
    if (lane == 0)
      pv = (s == 0) ? rawhead : rdlane_f(rawtail[s - 1], 63);
    prev[s] = pv;                          // wave-start boundary: step 0 here,
  }                                        // fixed up in the combine below.

  // ---- Local unwrap; exact per-chunk step counts.
  int n[kNS];
#pragma unroll
  for (int s = 0; s < kNS; ++s) {
    float run = 0.0f;
    if (act[s]) {
      float p = prev[s];
#pragma unroll
      for (int k = 0; k < 4; ++k) {
        const float cur = ph[s][k];
        const float d = cur - p;
        p = cur;
        float step = 0.0f;
        if (d < -kPi) step = kTwoPi;
        else if (d > kPi) step = -kTwoPi;
        run += step;
        ph[s][k] = cur + run;
      }
    }
    n[s] = __float2int_rn(run * kInv2Pi);  // exact: |n| <= 4
  }

  // ---- ONE packed-int wave scan (3 x 10-bit biased fields, no carries).
  const unsigned packed = (unsigned)(n[0] + 8) |
                          ((unsigned)(n[1] + 8) << 10) |
                          ((unsigned)(n[2] + 8) << 20);
  unsigned incp = packed;
#pragma unroll
  for (int d = 1; d < 64; d <<= 1) {
    const unsigned up = (unsigned)__shfl_up((int)incp, d);
    if (lane >= d) incp += up;
  }
  const unsigned excp = incp - packed;     // exclusive, field-wise
  const unsigned i63 = (unsigned)__builtin_amdgcn_readlane((int)incp, 63);
  const int tot0 = (int)(i63 & 1023u) - 512;
  const int tot1 = (int)((i63 >> 10) & 1023u) - 512;
  const int tot2 = (int)((i63 >> 20) & 1023u) - 512;
  // within-wave correction count for chunk (s, lane):
  int cnt[kNS];
  cnt[0] = (int)(excp & 1023u) - 8 * lane;
  cnt[1] = (int)((excp >> 10) & 1023u) - 8 * lane + tot0;
  cnt[2] = (int)((excp >> 20) & 1023u) - 8 * lane + tot0 + tot1;

  // ---- Per-lane min/max over corrected values; DPP wave reduce.
  float mn = __builtin_inff();
  float mx = -__builtin_inff();
  float woff[kNS];
#pragma unroll
  for (int s = 0; s < kNS; ++s) {
    woff[s] = (float)cnt[s] * kTwoPi;
    if (act[s]) {
#pragma unroll
      for (int k = 0; k < 4; ++k) {
        const float u = ph[s][k] + woff[s];
        mn = fminf(mn, u);
        mx = fmaxf(mx, u);
      }
    }
  }
  wave_minmax63(mn, mx);

  // ---- Publish 5 floats per wave; one barrier.
  const float tailv = rdlane_f(rawtail[2], tail_lane);   // wave's last raw phase
  const float headv = rdlane_f(rawhead, 0);
  if (lane == 63) {
    s_comb[0][wave] = headv;
    s_comb[1][wave] = tailv;
    s_comb[2][wave] = (float)(tot0 + tot1 + tot2);
    s_comb[3][wave] = mn;
    s_comb[4][wave] = mx;
  }
  sync_lds();   // the only barrier (lgkm only)

  // ---- Combine (all threads redundantly; 5 x ds_read_b128).
  const v4f hd = *reinterpret_cast<const v4f*>(&s_comb[0][0]);
  const v4f tl = *reinterpret_cast<const v4f*>(&s_comb[1][0]);
  const v4f tw = *reinterpret_cast<const v4f*>(&s_comb[2][0]);
  const v4f wm = *reinterpret_cast<const v4f*>(&s_comb[3][0]);
  const v4f wx = *reinterpret_cast<const v4f*>(&s_comb[4][0]);

  // wave-boundary steps (same predicate as reference) + cumulative counts
  float C[4];
  C[0] = 0.0f;
  {
    float cum = 0.0f;
    const float hds[4] = {hd.x, hd.y, hd.z, hd.w};
    const float tls[4] = {tl.x, tl.y, tl.z, tl.w};
    const float tws[4] = {tw.x, tw.y, tw.z, tw.w};
#pragma unroll
    for (int w = 1; w < 4; ++w) {
      const float d = hds[w] - tls[w - 1];
      float nb = 0.0f;
      if (d < -kPi) nb = 1.0f;
      else if (d > kPi) nb = -1.0f;
      cum += tws[w - 1] + nb;
      C[w] = cum;
    }
  }
  const float wms[4] = {wm.x, wm.y, wm.z, wm.w};
  const float wxs[4] = {wx.x, wx.y, wx.z, wx.w};
  float gmn = __builtin_inff();
  float gmx = -__builtin_inff();
#pragma unroll
  for (int w = 0; w < 4; ++w) {
    gmn = fminf(gmn, wms[w] + C[w] * kTwoPi);
    gmx = fmaxf(gmx, wxs[w] + C[w] * kTwoPi);
  }
  const float inv = 1.0f / (gmx - gmn + 1e-8f);
  const float myC = C[wave] * kTwoPi;

  // ---- Normalized phase out (nt, coalesced).
#pragma unroll
  for (int s = 0; s < kNS; ++s) {
    if (act[s]) {
      const float base = myC + woff[s] - gmn;
      v4f o;
      o.x = (ph[s][0] + base) * inv;
      o.y = (ph[s][1] + base) * inv;
      o.z = (ph[s][2] + base) * inv;
      o.w = (ph[s][3] + base) * inv;
      __builtin_nontemporal_store(o, reinterpret_cast<v4f*>(ph_out + offs[s]));
    }
  }
}

extern "C" void kernel_launch(void* const* d_in, const int* in_sizes, int n_in,
                              void* d_out, int out_size, void* d_ws, size_t ws_size,
                              hipStream_t stream) {
  const float* xr = (const float*)d_in[0];
  const float* xi = (const float*)d_in[1];
  float* out = (float*)d_out;
  coherent_polar_kernel<<<dim3(kGridB), dim3(kThreads), 0, stream>>>(xr, xi, out);
}